// Round 2
// baseline (2328.522 us; speedup 1.0000x reference)
//
#include <hip/hip_runtime.h>
#include <hip/hip_bf16.h>
#include <stdint.h>
#include <cstddef>

// Problem constants
#define BB  2
#define CC  512
#define TT  32
#define HWP 196   // H*W = 14*14
#define NH  8
#define KWIN 9
#define CID 64    // C / N
#define PPAD 4    // (K-1)/2
#define TP  40    // T + 2P

typedef unsigned short u16;
typedef unsigned int   u32;

__device__ __forceinline__ float bf2f(u16 h) {
    u32 u = ((u32)h) << 16;
    return __uint_as_float(u);
}
__device__ __forceinline__ u16 f2bf(float f) {
    u32 u = __float_as_uint(f);
    u32 r = (u + 0x7fffu + ((u >> 16) & 1u)) >> 16;
    return (u16)r;
}

// ---------------------------------------------------------------------------
// Projection kernel: out[oc, p] = sum_c W[oc, c] * x[b, c, frame, p] + bias[oc]
// One block = (b, n, frame-id, half of 32 output channels).
// frame-id 0..31 -> Q (t = frame), 32..71 -> K (tp = frame-32), 72..111 -> V.
// K/V frames with x out of range produce bias-only (matches zero-pad ref).
// fp32 inputs; bf16 workspace output [pos][CI] rows (MFMA-friendly later).
// LDS: W^T staged in two c-passes of 256 x 36 fp32 = 36 KiB (< 64 KiB).
// ---------------------------------------------------------------------------
__global__ __launch_bounds__(256) void proj_kernel(
    const float* __restrict__ x,
    const float* __restrict__ Wq, const float* __restrict__ bq,
    const float* __restrict__ Wk, const float* __restrict__ bk,
    const float* __restrict__ Wv, const float* __restrict__ bv,
    u16* __restrict__ Qout, u16* __restrict__ Kout, u16* __restrict__ Vout)
{
    // WT[c][i]: 256 rows x 32 ch, padded to 36 floats/row (16B-aligned float4)
    __shared__ float WT[256 * 36];

    int bx = blockIdx.x;
    int half = bx & 1; bx >>= 1;
    int frame = bx % 112; bx /= 112;
    int n = bx & 7;
    int b = bx >> 3;

    const float* Wsel; const float* bsel; u16* outp; int xframe;
    if (frame < 32) {
        Wsel = Wq; bsel = bq; xframe = frame;
        outp = Qout + (size_t)((b * NH + n) * TT + frame) * (HWP * CID);
    } else if (frame < 72) {
        int tp = frame - 32;
        Wsel = Wk; bsel = bk; xframe = tp - PPAD;
        outp = Kout + (size_t)((b * NH + n) * TP + tp) * (HWP * CID);
    } else {
        int tp = frame - 72;
        Wsel = Wv; bsel = bv; xframe = tp - PPAD;
        outp = Vout + (size_t)((b * NH + n) * TP + tp) * (HWP * CID);
    }
    const float* Wbase = Wsel + (size_t)(n * CID + half * 32) * CC;
    const float* bbase = bsel + n * CID + half * 32;

    int tid = threadIdx.x;
    int p = tid;
    bool valid = (xframe >= 0 && xframe < TT);

    float acc[32];
    #pragma unroll
    for (int i = 0; i < 32; i++) acc[i] = bbase[i];   // uniform (scalarizes)

    for (int cp = 0; cp < 2; cp++) {
        __syncthreads();
        // Stage W^T tile: rows c (256), cols i (32). Coalesced global reads.
        for (int e = tid; e < 32 * 256; e += 256) {
            int i = e >> 8;
            int c = e & 255;
            WT[c * 36 + i] = Wbase[(size_t)i * CC + cp * 256 + c];
        }
        __syncthreads();

        if (p < HWP && valid) {
            const float* xp = x + ((size_t)(b * CC + cp * 256) * TT + xframe) * HWP + p;
            #pragma unroll 4
            for (int c = 0; c < 256; c++) {
                float xv = xp[(size_t)c * (TT * HWP)];
                const float4* wrow = (const float4*)&WT[c * 36];
                #pragma unroll
                for (int i4 = 0; i4 < 8; i4++) {
                    float4 w = wrow[i4];  // LDS broadcast (all lanes same addr)
                    acc[i4 * 4 + 0] = fmaf(xv, w.x, acc[i4 * 4 + 0]);
                    acc[i4 * 4 + 1] = fmaf(xv, w.y, acc[i4 * 4 + 1]);
                    acc[i4 * 4 + 2] = fmaf(xv, w.z, acc[i4 * 4 + 2]);
                    acc[i4 * 4 + 3] = fmaf(xv, w.w, acc[i4 * 4 + 3]);
                }
            }
        }
    }

    if (p < HWP) {
        // Store 32 contiguous bf16 (packed as 16 dwords)
        u32* op32 = (u32*)(outp + (size_t)p * CID + half * 32);
        #pragma unroll
        for (int k = 0; k < 16; k++) {
            u32 pk = (u32)f2bf(acc[2 * k]) | ((u32)f2bf(acc[2 * k + 1]) << 16);
            op32[k] = pk;
        }
    }
}

// ---------------------------------------------------------------------------
// Flash attention kernel: one block = (b, n, t). Thread-per-query online
// softmax; K/V staged per half-frame (98 keys) as fp32 in LDS; all inner-loop
// LDS reads are wave-broadcast float4 (conflict-free). Epilogue adds residual
// (fp32 x) and stores fp32 z.
// ---------------------------------------------------------------------------
__global__ __launch_bounds__(256, 2) void attn_kernel(
    const float* __restrict__ x,
    const u16* __restrict__ Qb, const u16* __restrict__ Kb,
    const u16* __restrict__ Vb, float* __restrict__ zout)
{
    __shared__ float sK[98 * 64];
    __shared__ float sV[98 * 64];

    int bx = blockIdx.x;
    int t = bx & 31; bx >>= 5;
    int n = bx & 7;
    int b = bx >> 3;

    int tid = threadIdx.x;
    int p = tid;
    const size_t bn = (size_t)(b * NH + n);

    float q[64], y[64];
    float m_run = -1e30f, l_run = 0.f;

    if (p < HWP) {
        const u16* qsrc = Qb + (bn * TT + t) * (HWP * CID) + (size_t)p * CID;
        #pragma unroll
        for (int i = 0; i < 64; i++) q[i] = bf2f(qsrc[i]);
        #pragma unroll
        for (int i = 0; i < 64; i++) y[i] = 0.f;
    }

    for (int hh = 0; hh < 18; hh++) {
        int f = hh >> 1, hs = hh & 1;
        const u16* Ksrc = Kb + (bn * TP + (t + f)) * (HWP * CID) + hs * (98 * CID);
        const u16* Vsrc = Vb + (bn * TP + (t + f)) * (HWP * CID) + hs * (98 * CID);
        __syncthreads();  // protect previous iteration's reads
        for (int e = tid; e < 98 * 64; e += 256) {
            sK[e] = bf2f(Ksrc[e]);
            sV[e] = bf2f(Vsrc[e]);
        }
        __syncthreads();

        if (p < HWP) {
            for (int ch = 0; ch < 7; ch++) {   // 7 chunks x 14 keys = 98
                int base = ch * 14;
                float s[14];
                #pragma unroll
                for (int j = 0; j < 14; j++) {
                    const float4* kr = (const float4*)&sK[(base + j) * 64];
                    float a0 = 0.f, a1 = 0.f, a2 = 0.f, a3 = 0.f;
                    #pragma unroll
                    for (int i4 = 0; i4 < 16; i4++) {
                        float4 kv = kr[i4];  // broadcast
                        a0 = fmaf(q[i4 * 4 + 0], kv.x, a0);
                        a1 = fmaf(q[i4 * 4 + 1], kv.y, a1);
                        a2 = fmaf(q[i4 * 4 + 2], kv.z, a2);
                        a3 = fmaf(q[i4 * 4 + 3], kv.w, a3);
                    }
                    s[j] = (a0 + a1) + (a2 + a3);
                }
                float cmax = s[0];
                #pragma unroll
                for (int j = 1; j < 14; j++) cmax = fmaxf(cmax, s[j]);
                float mnew = fmaxf(m_run, cmax);
                float scale = __expf(m_run - mnew);
                l_run *= scale;
                #pragma unroll
                for (int i = 0; i < 64; i++) y[i] *= scale;
                #pragma unroll
                for (int j = 0; j < 14; j++) {
                    float pj = __expf(s[j] - mnew);
                    l_run += pj;
                    const float4* vr = (const float4*)&sV[(base + j) * 64];
                    #pragma unroll
                    for (int i4 = 0; i4 < 16; i4++) {
                        float4 vv = vr[i4];  // broadcast
                        y[i4 * 4 + 0] = fmaf(pj, vv.x, y[i4 * 4 + 0]);
                        y[i4 * 4 + 1] = fmaf(pj, vv.y, y[i4 * 4 + 1]);
                        y[i4 * 4 + 2] = fmaf(pj, vv.z, y[i4 * 4 + 2]);
                        y[i4 * 4 + 3] = fmaf(pj, vv.w, y[i4 * 4 + 3]);
                    }
                }
                m_run = mnew;
            }
        }
    }

    if (p < HWP) {
        float inv = 1.0f / l_run;
        const size_t cbase = ((size_t)(b * CC + n * CID) * TT + t) * HWP + p;
        #pragma unroll
        for (int i = 0; i < 64; i++) {
            float zv = y[i] * inv + x[cbase + (size_t)i * (TT * HWP)];
            zout[cbase + (size_t)i * (TT * HWP)] = zv;
        }
    }
}

// ---------------------------------------------------------------------------
extern "C" void kernel_launch(void* const* d_in, const int* in_sizes, int n_in,
                              void* d_out, int out_size, void* d_ws, size_t ws_size,
                              hipStream_t stream) {
    const float* x  = (const float*)d_in[0];
    const float* Wq = (const float*)d_in[1];
    const float* bq = (const float*)d_in[2];
    const float* Wk = (const float*)d_in[3];
    const float* bk = (const float*)d_in[4];
    const float* Wv = (const float*)d_in[5];
    const float* bv = (const float*)d_in[6];
    float* z = (float*)d_out;

    // Workspace layout (bf16):
    //   Q: [B][N][T ][HW][CI]  = 6,422,528 elems
    //   K: [B][N][Tp][HW][CI]  = 8,028,160 elems
    //   V: [B][N][Tp][HW][CI]  = 8,028,160 elems   (total ~45 MB)
    u16* Qw = (u16*)d_ws;
    u16* Kw = Qw + (size_t)BB * NH * TT * HWP * CID;
    u16* Vw = Kw + (size_t)BB * NH * TP * HWP * CID;

    // 2 (b) * 8 (n) * 112 (frames: 32 q + 40 k + 40 v) * 2 (channel halves)
    proj_kernel<<<3584, 256, 0, stream>>>(x, Wq, bq, Wk, bk, Wv, bv, Qw, Kw, Vw);
    // 2 (b) * 8 (n) * 32 (t)
    attn_kernel<<<512, 256, 0, stream>>>(x, Qw, Kw, Vw, z);
}

// Round 3
// 711.875 us; speedup vs baseline: 3.2710x; 3.2710x over previous
//
#include <hip/hip_runtime.h>
#include <hip/hip_bf16.h>
#include <stdint.h>
#include <cstddef>

// Problem constants
#define BB  2
#define CC  512
#define TT  32
#define HWP 196   // H*W = 14*14
#define NH  8
#define KWIN 9
#define CID 64    // C / N
#define PPAD 4    // (K-1)/2
#define TP  40    // T + 2P
#define NKEY 1764 // KWIN * HWP
#define NCHUNK 28 // ceil(1764/64)

typedef unsigned short u16;
typedef unsigned int   u32;
typedef __attribute__((ext_vector_type(8))) short short8;
typedef __attribute__((ext_vector_type(4))) float floatx4;

__device__ __forceinline__ float bf2f(u16 h) {
    u32 u = ((u32)h) << 16;
    return __uint_as_float(u);
}
__device__ __forceinline__ u16 f2bf(float f) {
    u32 u = __float_as_uint(f);
    u32 r = (u + 0x7fffu + ((u >> 16) & 1u)) >> 16;
    return (u16)r;
}
__device__ __forceinline__ u32 pack2bf(float a, float b) {
    return (u32)f2bf(a) | ((u32)f2bf(b) << 16);
}

// ---------------------------------------------------------------------------
// Projection kernel (unchanged, verified): out[oc,p] = sum_c W[oc,c]*x[..] + b
// ---------------------------------------------------------------------------
__global__ __launch_bounds__(256) void proj_kernel(
    const float* __restrict__ x,
    const float* __restrict__ Wq, const float* __restrict__ bq,
    const float* __restrict__ Wk, const float* __restrict__ bk,
    const float* __restrict__ Wv, const float* __restrict__ bv,
    u16* __restrict__ Qout, u16* __restrict__ Kout, u16* __restrict__ Vout)
{
    __shared__ float WT[256 * 36];

    int bx = blockIdx.x;
    int half = bx & 1; bx >>= 1;
    int frame = bx % 112; bx /= 112;
    int n = bx & 7;
    int b = bx >> 3;

    const float* Wsel; const float* bsel; u16* outp; int xframe;
    if (frame < 32) {
        Wsel = Wq; bsel = bq; xframe = frame;
        outp = Qout + (size_t)((b * NH + n) * TT + frame) * (HWP * CID);
    } else if (frame < 72) {
        int tp = frame - 32;
        Wsel = Wk; bsel = bk; xframe = tp - PPAD;
        outp = Kout + (size_t)((b * NH + n) * TP + tp) * (HWP * CID);
    } else {
        int tp = frame - 72;
        Wsel = Wv; bsel = bv; xframe = tp - PPAD;
        outp = Vout + (size_t)((b * NH + n) * TP + tp) * (HWP * CID);
    }
    const float* Wbase = Wsel + (size_t)(n * CID + half * 32) * CC;
    const float* bbase = bsel + n * CID + half * 32;

    int tid = threadIdx.x;
    int p = tid;
    bool valid = (xframe >= 0 && xframe < TT);

    float acc[32];
    #pragma unroll
    for (int i = 0; i < 32; i++) acc[i] = bbase[i];

    for (int cp = 0; cp < 2; cp++) {
        __syncthreads();
        for (int e = tid; e < 32 * 256; e += 256) {
            int i = e >> 8;
            int c = e & 255;
            WT[c * 36 + i] = Wbase[(size_t)i * CC + cp * 256 + c];
        }
        __syncthreads();

        if (p < HWP && valid) {
            const float* xp = x + ((size_t)(b * CC + cp * 256) * TT + xframe) * HWP + p;
            #pragma unroll 4
            for (int c = 0; c < 256; c++) {
                float xv = xp[(size_t)c * (TT * HWP)];
                const float4* wrow = (const float4*)&WT[c * 36];
                #pragma unroll
                for (int i4 = 0; i4 < 8; i4++) {
                    float4 w = wrow[i4];
                    acc[i4 * 4 + 0] = fmaf(xv, w.x, acc[i4 * 4 + 0]);
                    acc[i4 * 4 + 1] = fmaf(xv, w.y, acc[i4 * 4 + 1]);
                    acc[i4 * 4 + 2] = fmaf(xv, w.z, acc[i4 * 4 + 2]);
                    acc[i4 * 4 + 3] = fmaf(xv, w.w, acc[i4 * 4 + 3]);
                }
            }
        }
    }

    if (p < HWP) {
        u32* op32 = (u32*)(outp + (size_t)p * CID + half * 32);
        #pragma unroll
        for (int k = 0; k < 16; k++) {
            op32[k] = pack2bf(acc[2 * k], acc[2 * k + 1]);
        }
    }
}

// ---------------------------------------------------------------------------
// MFMA flash attention. One block = (b,n,t, M-half). 2 waves/block, each wave
// owns 4 M-tiles of 16 queries (M padded 196->256). Per 64-key chunk:
//   S^T tiles via mfma(A=K, B=Q) -> D[key][q], col=lane&15=q, row=quad*4+reg.
//   Online softmax: per-lane 16-reg reduce + shfl_xor(16,32).
//   P stays in registers: S^T regs ARE the PV A-frags under the key
//   permutation natkey(quad,j)=16*(j>>2)+4*quad+(j&3); V is staged into LDS
//   transposed with the same permutation, so B-frags read contiguously.
//   Y += P*V via mfma(A=P, B=Vt) -> D[q][ci], row=quad*4+reg=q, col=ci.
// ---------------------------------------------------------------------------
__global__ __launch_bounds__(128, 2) void attn_mfma(
    const float* __restrict__ x,
    const u16* __restrict__ Qb, const u16* __restrict__ Kb,
    const u16* __restrict__ Vb, float* __restrict__ zout)
{
    __shared__ u16 sVt[64 * 72];   // [ci][kA-permuted], pitch 72 (144B, 16B-aligned)

    int bx = blockIdx.x;
    int bh = bx & 1; bx >>= 1;
    int t = bx & 31; bx >>= 5;
    int n = bx & 7;
    int b = bx >> 3;
    int bn = b * NH + n;

    int tid = threadIdx.x;
    int wave = tid >> 6;
    int lane = tid & 63;
    int quad = lane >> 4;
    int l15 = lane & 15;
    int tilebase = (bh * 2 + wave) * 4;   // 4 tiles of 16 rows each

    const size_t kslab = (size_t)bn * (TP * HWP);   // K/V row base for this (b,n)
    const int trow = t * HWP;                       // window start row (rel.)

    // Persistent Q B-frags: B[n=q=l15][k=c], k-chunk cc: elems cc*32+quad*8..+7
    short8 qfrag[4][2];
    #pragma unroll
    for (int tt = 0; tt < 4; tt++) {
        int qrow = (tilebase + tt) * 16 + l15;
        qrow = qrow < HWP ? qrow : (HWP - 1);      // clamp padded rows
        const uint4* qp = (const uint4*)(Qb + ((size_t)(bn * TT + t) * HWP + qrow) * CID);
        qfrag[tt][0] = *(const short8*)&qp[quad];
        qfrag[tt][1] = *(const short8*)&qp[4 + quad];
    }

    floatx4 acc[4][4];   // [tile][ci-group]
    #pragma unroll
    for (int tt = 0; tt < 4; tt++)
        #pragma unroll
        for (int cg = 0; cg < 4; cg++)
            acc[tt][cg] = (floatx4){0.f, 0.f, 0.f, 0.f};
    float m_run[4], l_run[4];
    #pragma unroll
    for (int tt = 0; tt < 4; tt++) { m_run[tt] = -1e30f; l_run[tt] = 0.f; }

    for (int chunk = 0; chunk < NCHUNK; chunk++) {
        int keybase = chunk * 64;
        __syncthreads();   // protect prior iteration's sVt reads
        {
            // Stage V chunk transposed+permuted: thread -> (key, 32 ci)
            int key = tid >> 1;
            int ci0 = (tid & 1) << 5;
            int row = trow + keybase + key;
            row = row < (TP * HWP - 1) ? row : (TP * HWP - 1);  // clamp (masked keys)
            const u32* src = (const u32*)(Vb + (kslab + row) * CID + ci0);
            int kk = key & 31;
            int col = ((key >> 5) << 5) + ((kk >> 2) & 3) * 8 + (kk >> 4) * 4 + (kk & 3);
            u16* dst = sVt + col;
            #pragma unroll
            for (int w = 0; w < 16; w++) {
                u32 v = src[w];
                dst[(ci0 + 2 * w) * 72]     = (u16)(v & 0xffffu);
                dst[(ci0 + 2 * w + 1) * 72] = (u16)(v >> 16);
            }
        }
        __syncthreads();

        // K A-frags: A[m=key=l15][k=c], shared across M-tiles
        short8 kfrag[4][2];
        #pragma unroll
        for (int g = 0; g < 4; g++) {
            int row = trow + keybase + g * 16 + l15;
            row = row < (TP * HWP - 1) ? row : (TP * HWP - 1);
            const uint4* kp = (const uint4*)(Kb + (kslab + row) * CID);
            kfrag[g][0] = *(const short8*)&kp[quad];
            kfrag[g][1] = *(const short8*)&kp[4 + quad];
        }
        // V B-frags from LDS: B[n=ci=l15][k=key-slot], shared across M-tiles
        short8 vfrag[4][2];
        #pragma unroll
        for (int cg = 0; cg < 4; cg++) {
            const u16* vp = sVt + (cg * 16 + l15) * 72;
            vfrag[cg][0] = *(const short8*)(vp + quad * 8);
            vfrag[cg][1] = *(const short8*)(vp + 32 + quad * 8);
        }

        bool lastchunk = (chunk == NCHUNK - 1);

        #pragma unroll
        for (int tt = 0; tt < 4; tt++) {
            // S^T = K . Q^T  -> D[key][q]
            floatx4 sc[4];
            #pragma unroll
            for (int g = 0; g < 4; g++) {
                sc[g] = (floatx4){0.f, 0.f, 0.f, 0.f};
                sc[g] = __builtin_amdgcn_mfma_f32_16x16x32_bf16(kfrag[g][0], qfrag[tt][0], sc[g], 0, 0, 0);
                sc[g] = __builtin_amdgcn_mfma_f32_16x16x32_bf16(kfrag[g][1], qfrag[tt][1], sc[g], 0, 0, 0);
            }
            if (lastchunk) {
                #pragma unroll
                for (int g = 0; g < 4; g++) {
                    int kb = keybase + g * 16 + quad * 4;
                    #pragma unroll
                    for (int r = 0; r < 4; r++)
                        if (kb + r >= NKEY) sc[g][r] = -1e30f;
                }
            }
            // row (q) max over 64 keys: 16 regs + lanes quad 0..3
            float cm = sc[0][0];
            #pragma unroll
            for (int g = 0; g < 4; g++)
                #pragma unroll
                for (int r = 0; r < 4; r++) cm = fmaxf(cm, sc[g][r]);
            cm = fmaxf(cm, __shfl_xor(cm, 16));
            cm = fmaxf(cm, __shfl_xor(cm, 32));
            float mnew = fmaxf(m_run[tt], cm);
            float alpha = __expf(m_run[tt] - mnew);
            m_run[tt] = mnew;

            float lsum = 0.f;
            u32 pw[8];
            #pragma unroll
            for (int g = 0; g < 4; g++) {
                float p0 = __expf(sc[g][0] - mnew);
                float p1 = __expf(sc[g][1] - mnew);
                float p2 = __expf(sc[g][2] - mnew);
                float p3 = __expf(sc[g][3] - mnew);
                lsum += (p0 + p1) + (p2 + p3);
                pw[g * 2 + 0] = pack2bf(p0, p1);
                pw[g * 2 + 1] = pack2bf(p2, p3);
            }
            lsum += __shfl_xor(lsum, 16);
            lsum += __shfl_xor(lsum, 32);
            l_run[tt] = l_run[tt] * alpha + lsum;

            // rescale factors per output row q=quad*4+r (alpha indexed by q=l15)
            float a0 = __shfl(alpha, quad * 4 + 0);
            float a1 = __shfl(alpha, quad * 4 + 1);
            float a2 = __shfl(alpha, quad * 4 + 2);
            float a3 = __shfl(alpha, quad * 4 + 3);

            // P A-frags: S^T regs in natural order under the key permutation
            union { u32 w[4]; short8 s; } pf0, pf1;
            pf0.w[0] = pw[0]; pf0.w[1] = pw[1]; pf0.w[2] = pw[2]; pf0.w[3] = pw[3];
            pf1.w[0] = pw[4]; pf1.w[1] = pw[5]; pf1.w[2] = pw[6]; pf1.w[3] = pw[7];

            #pragma unroll
            for (int cg = 0; cg < 4; cg++) {
                floatx4 ac = acc[tt][cg];
                ac[0] *= a0; ac[1] *= a1; ac[2] *= a2; ac[3] *= a3;
                ac = __builtin_amdgcn_mfma_f32_16x16x32_bf16(pf0.s, vfrag[cg][0], ac, 0, 0, 0);
                ac = __builtin_amdgcn_mfma_f32_16x16x32_bf16(pf1.s, vfrag[cg][1], ac, 0, 0, 0);
                acc[tt][cg] = ac;
            }
        }
    }

    // Epilogue: z = Y/l + x. Y row q=quad*4+r, col ci=cg*16+l15.
    #pragma unroll
    for (int tt = 0; tt < 4; tt++) {
        float linv = 1.0f / l_run[tt];
        float li[4];
        li[0] = __shfl(linv, quad * 4 + 0);
        li[1] = __shfl(linv, quad * 4 + 1);
        li[2] = __shfl(linv, quad * 4 + 2);
        li[3] = __shfl(linv, quad * 4 + 3);
        #pragma unroll
        for (int r = 0; r < 4; r++) {
            int p = (tilebase + tt) * 16 + quad * 4 + r;
            if (p < HWP) {
                #pragma unroll
                for (int cg = 0; cg < 4; cg++) {
                    int c = n * CID + cg * 16 + l15;
                    size_t addr = ((size_t)(b * CC + c) * TT + t) * HWP + p;
                    zout[addr] = acc[tt][cg][r] * li[r] + x[addr];
                }
            }
        }
    }
}

// ---------------------------------------------------------------------------
extern "C" void kernel_launch(void* const* d_in, const int* in_sizes, int n_in,
                              void* d_out, int out_size, void* d_ws, size_t ws_size,
                              hipStream_t stream) {
    const float* x  = (const float*)d_in[0];
    const float* Wq = (const float*)d_in[1];
    const float* bq = (const float*)d_in[2];
    const float* Wk = (const float*)d_in[3];
    const float* bk = (const float*)d_in[4];
    const float* Wv = (const float*)d_in[5];
    const float* bv = (const float*)d_in[6];
    float* z = (float*)d_out;

    // Workspace (bf16): Q [B][N][T][HW][CI], K/V [B][N][Tp][HW][CI]
    u16* Qw = (u16*)d_ws;
    u16* Kw = Qw + (size_t)BB * NH * TT * HWP * CID;
    u16* Vw = Kw + (size_t)BB * NH * TP * HWP * CID;

    proj_kernel<<<3584, 256, 0, stream>>>(x, Wq, bq, Wk, bk, Wv, bv, Qw, Kw, Vw);
    // 2 (b) * 8 (n) * 32 (t) * 2 (M-halves)
    attn_mfma<<<1024, 128, 0, stream>>>(x, Qw, Kw, Vw, z);
}

// Round 4
// 329.946 us; speedup vs baseline: 7.0573x; 2.1575x over previous
//
#include <hip/hip_runtime.h>
#include <hip/hip_bf16.h>
#include <stdint.h>
#include <cstddef>

// Problem constants
#define BB  2
#define CC  512
#define TT  32
#define HWP 196   // H*W = 14*14
#define NH  8
#define KWIN 9
#define CID 64    // C / N
#define PPAD 4    // (K-1)/2
#define TP  40    // T + 2P
#define NKEY 1764 // KWIN * HWP
#define NCHUNK 28 // ceil(1764/64)
#define MTOT 12544  // BB*TT*HWP
#define NTOT 1536   // 3*CC (Q|K|V output channels)

typedef unsigned short u16;
typedef unsigned int   u32;
typedef __attribute__((ext_vector_type(8))) short short8;
typedef __attribute__((ext_vector_type(4))) float floatx4;

__device__ __forceinline__ float bf2f(u16 h) {
    u32 u = ((u32)h) << 16;
    return __uint_as_float(u);
}
__device__ __forceinline__ u16 f2bf(float f) {
    u32 u = __float_as_uint(f);
    u32 r = (u + 0x7fffu + ((u >> 16) & 1u)) >> 16;
    return (u16)r;
}
__device__ __forceinline__ u32 pack2bf(float a, float b) {
    return (u32)f2bf(a) | ((u32)f2bf(b) << 16);
}

// ---------------------------------------------------------------------------
// Prep 1: W concat + fp32->bf16.  Wbf[oc][c], oc = kind*512 + n*64 + ci.
// ---------------------------------------------------------------------------
__global__ __launch_bounds__(256) void convert_w(
    const float* __restrict__ Wq, const float* __restrict__ Wk,
    const float* __restrict__ Wv, u16* __restrict__ Wbf)
{
    int id = blockIdx.x * 256 + threadIdx.x;      // one u32 (2 elems) each
    if (id >= NTOT * CC / 2) return;
    int c2 = id & 255;                            // c = 2*c2
    int oc = id >> 8;
    int kind = oc >> 9;
    int idx = oc & 511;
    const float* src = (kind == 0 ? Wq : (kind == 1 ? Wk : Wv)) + (size_t)idx * CC + c2 * 2;
    ((u32*)Wbf)[id] = pack2bf(src[0], src[1]);
}

// ---------------------------------------------------------------------------
// Prep 2: transpose x[b][c][t][p] fp32 -> xt[(b*T+t)*HW+p][c] bf16.
// Block = (b, t, c-tile of 64). LDS 64x197 fp32, 2-way conflicts only (free).
// ---------------------------------------------------------------------------
__global__ __launch_bounds__(256) void transpose_x(
    const float* __restrict__ x, u16* __restrict__ xt)
{
    __shared__ float T[64 * 197];
    int bx = blockIdx.x;
    int ct = bx & 7; bx >>= 3;
    int t = bx & 31;
    int b = bx >> 5;
    int tid = threadIdx.x;
    const float* src = x + ((size_t)(b * CC + ct * 64) * TT + t) * HWP;
    for (int i = tid; i < 64 * HWP; i += 256) {
        int c = i / HWP;
        int p = i - c * HWP;
        T[c * 197 + p] = src[(size_t)c * (TT * HWP) + p];
    }
    __syncthreads();
    u16* dst = xt + (size_t)((b * TT + t) * HWP) * CC + ct * 64;
    for (int i = tid; i < HWP * 64; i += 256) {
        int p = i >> 6;
        int c = i & 63;
        dst[(size_t)p * CC + c] = f2bf(T[c * 197 + p]);
    }
}

// ---------------------------------------------------------------------------
// Prep 3: fill K/V zero-pad frames (tp in {0..3, 36..39}) with bias only.
// ---------------------------------------------------------------------------
__global__ __launch_bounds__(256) void pad_fill(
    const float* __restrict__ bk, const float* __restrict__ bv,
    u16* __restrict__ Kout, u16* __restrict__ Vout)
{
    int id = blockIdx.x * 256 + threadIdx.x;     // one u32 (2 ci) each
    const int per = 2 * NH * 8 * HWP * 32;       // 802816 per tensor
    if (id >= 2 * per) return;
    int kv = id >= per;
    int i = kv ? id - per : id;
    int ci2 = i & 31; i >>= 5;
    int p = i % HWP;  i /= HWP;
    int fr = i & 7;   i >>= 3;
    int head = i & 7;
    int b = i >> 3;
    int tp = fr < 4 ? fr : fr + 32;
    const float* bias = (kv ? bv : bk) + head * CID + ci2 * 2;
    u32* dst = (u32*)(kv ? Vout : Kout);
    size_t addr = (((size_t)(b * NH + head) * TP + tp) * HWP + p) * 32 + ci2;
    dst[addr] = pack2bf(bias[0], bias[1]);
}

// ---------------------------------------------------------------------------
// MFMA projection GEMM: Out^T[m=(b,t,p), n=oc] = xt[m,c] . Wbf[n,c] + bias[n].
// Block = 4 waves; wave does M64 x N64 (16 frags). M-tiles 196, N-blocks 6.
// Operands straight from global (W L2-resident, xt L3-resident).
// Epilogue scatters to Q/K/V workspace rows [pos][CI] (attn-ready layout).
// ---------------------------------------------------------------------------
__global__ __launch_bounds__(256) void proj_gemm(
    const u16* __restrict__ xt, const u16* __restrict__ Wbf,
    const float* __restrict__ bq, const float* __restrict__ bk,
    const float* __restrict__ bv,
    u16* __restrict__ Qout, u16* __restrict__ Kout, u16* __restrict__ Vout)
{
    int bx = blockIdx.x;
    int nb = bx % 6;
    int mt = bx / 6;
    int tid = threadIdx.x;
    int wave = tid >> 6, lane = tid & 63, quad = lane >> 4, l15 = lane & 15;
    int mbase = mt * 64;
    int nbase = nb * 256 + wave * 64;

    floatx4 acc[4][4];
    #pragma unroll
    for (int ms = 0; ms < 4; ms++)
        #pragma unroll
        for (int ns = 0; ns < 4; ns++)
            acc[ms][ns] = (floatx4){0.f, 0.f, 0.f, 0.f};

    const u16* ap[4];
    const u16* bp[4];
    #pragma unroll
    for (int ms = 0; ms < 4; ms++)
        ap[ms] = xt + (size_t)(mbase + ms * 16 + l15) * CC + quad * 8;
    #pragma unroll
    for (int ns = 0; ns < 4; ns++)
        bp[ns] = Wbf + (size_t)(nbase + ns * 16 + l15) * CC + quad * 8;

    #pragma unroll 2
    for (int kc = 0; kc < 16; kc++) {
        short8 af[4], bf[4];
        #pragma unroll
        for (int ms = 0; ms < 4; ms++) af[ms] = *(const short8*)(ap[ms] + kc * 32);
        #pragma unroll
        for (int ns = 0; ns < 4; ns++) bf[ns] = *(const short8*)(bp[ns] + kc * 32);
        #pragma unroll
        for (int ms = 0; ms < 4; ms++)
            #pragma unroll
            for (int ns = 0; ns < 4; ns++)
                acc[ms][ns] = __builtin_amdgcn_mfma_f32_16x16x32_bf16(
                    af[ms], bf[ns], acc[ms][ns], 0, 0, 0);
    }

    // bias per n-subtile (per-lane column l15)
    float biasv[4];
    #pragma unroll
    for (int ns = 0; ns < 4; ns++) {
        int n = nbase + ns * 16 + l15;
        int kind = n >> 9;
        int idx = n & 511;
        const float* bpb = kind == 0 ? bq : (kind == 1 ? bk : bv);
        biasv[ns] = bpb[idx];
    }

    // Epilogue: D row m = quad*4+r, col n = l15.
    #pragma unroll
    for (int ms = 0; ms < 4; ms++) {
        #pragma unroll
        for (int r = 0; r < 4; r++) {
            int m = mbase + ms * 16 + quad * 4 + r;
            int b = m / (TT * HWP);
            int rem = m - b * (TT * HWP);
            int t = rem / HWP;
            int p = rem - t * HWP;
            #pragma unroll
            for (int ns = 0; ns < 4; ns++) {
                int n = nbase + ns * 16 + l15;
                int kind = n >> 9;          // uniform across lanes
                int idx = n & 511;
                int head = idx >> 6;
                int ci = idx & 63;
                float val = acc[ms][ns][r] + biasv[ns];
                if (kind == 0) {
                    Qout[(((size_t)(b * NH + head) * TT + t) * HWP + p) * CID + ci] = f2bf(val);
                } else {
                    u16* dst = (kind == 1) ? Kout : Vout;
                    dst[(((size_t)(b * NH + head) * TP + (t + PPAD)) * HWP + p) * CID + ci] = f2bf(val);
                }
            }
        }
    }
}

// ---------------------------------------------------------------------------
// Fallback projection kernel (round-3 verified), used if ws_size is small.
// ---------------------------------------------------------------------------
__global__ __launch_bounds__(256) void proj_kernel(
    const float* __restrict__ x,
    const float* __restrict__ Wq, const float* __restrict__ bq,
    const float* __restrict__ Wk, const float* __restrict__ bk,
    const float* __restrict__ Wv, const float* __restrict__ bv,
    u16* __restrict__ Qout, u16* __restrict__ Kout, u16* __restrict__ Vout)
{
    __shared__ float WT[256 * 36];

    int bx = blockIdx.x;
    int half = bx & 1; bx >>= 1;
    int frame = bx % 112; bx /= 112;
    int n = bx & 7;
    int b = bx >> 3;

    const float* Wsel; const float* bsel; u16* outp; int xframe;
    if (frame < 32) {
        Wsel = Wq; bsel = bq; xframe = frame;
        outp = Qout + (size_t)((b * NH + n) * TT + frame) * (HWP * CID);
    } else if (frame < 72) {
        int tp = frame - 32;
        Wsel = Wk; bsel = bk; xframe = tp - PPAD;
        outp = Kout + (size_t)((b * NH + n) * TP + tp) * (HWP * CID);
    } else {
        int tp = frame - 72;
        Wsel = Wv; bsel = bv; xframe = tp - PPAD;
        outp = Vout + (size_t)((b * NH + n) * TP + tp) * (HWP * CID);
    }
    const float* Wbase = Wsel + (size_t)(n * CID + half * 32) * CC;
    const float* bbase = bsel + n * CID + half * 32;

    int tid = threadIdx.x;
    int p = tid;
    bool valid = (xframe >= 0 && xframe < TT);

    float acc[32];
    #pragma unroll
    for (int i = 0; i < 32; i++) acc[i] = bbase[i];

    for (int cp = 0; cp < 2; cp++) {
        __syncthreads();
        for (int e = tid; e < 32 * 256; e += 256) {
            int i = e >> 8;
            int c = e & 255;
            WT[c * 36 + i] = Wbase[(size_t)i * CC + cp * 256 + c];
        }
        __syncthreads();

        if (p < HWP && valid) {
            const float* xp = x + ((size_t)(b * CC + cp * 256) * TT + xframe) * HWP + p;
            #pragma unroll 4
            for (int c = 0; c < 256; c++) {
                float xv = xp[(size_t)c * (TT * HWP)];
                const float4* wrow = (const float4*)&WT[c * 36];
                #pragma unroll
                for (int i4 = 0; i4 < 8; i4++) {
                    float4 w = wrow[i4];
                    acc[i4 * 4 + 0] = fmaf(xv, w.x, acc[i4 * 4 + 0]);
                    acc[i4 * 4 + 1] = fmaf(xv, w.y, acc[i4 * 4 + 1]);
                    acc[i4 * 4 + 2] = fmaf(xv, w.z, acc[i4 * 4 + 2]);
                    acc[i4 * 4 + 3] = fmaf(xv, w.w, acc[i4 * 4 + 3]);
                }
            }
        }
    }

    if (p < HWP) {
        u32* op32 = (u32*)(outp + (size_t)p * CID + half * 32);
        #pragma unroll
        for (int k = 0; k < 16; k++) op32[k] = pack2bf(acc[2 * k], acc[2 * k + 1]);
    }
}

// ---------------------------------------------------------------------------
// MFMA flash attention (round-3 verified, unchanged).
// ---------------------------------------------------------------------------
__global__ __launch_bounds__(128, 2) void attn_mfma(
    const float* __restrict__ x,
    const u16* __restrict__ Qb, const u16* __restrict__ Kb,
    const u16* __restrict__ Vb, float* __restrict__ zout)
{
    __shared__ u16 sVt[64 * 72];

    int bx = blockIdx.x;
    int bh = bx & 1; bx >>= 1;
    int t = bx & 31; bx >>= 5;
    int n = bx & 7;
    int b = bx >> 3;
    int bn = b * NH + n;

    int tid = threadIdx.x;
    int wave = tid >> 6;
    int lane = tid & 63;
    int quad = lane >> 4;
    int l15 = lane & 15;
    int tilebase = (bh * 2 + wave) * 4;

    const size_t kslab = (size_t)bn * (TP * HWP);
    const int trow = t * HWP;

    short8 qfrag[4][2];
    #pragma unroll
    for (int tt = 0; tt < 4; tt++) {
        int qrow = (tilebase + tt) * 16 + l15;
        qrow = qrow < HWP ? qrow : (HWP - 1);
        const uint4* qp = (const uint4*)(Qb + ((size_t)(bn * TT + t) * HWP + qrow) * CID);
        qfrag[tt][0] = *(const short8*)&qp[quad];
        qfrag[tt][1] = *(const short8*)&qp[4 + quad];
    }

    floatx4 acc[4][4];
    #pragma unroll
    for (int tt = 0; tt < 4; tt++)
        #pragma unroll
        for (int cg = 0; cg < 4; cg++)
            acc[tt][cg] = (floatx4){0.f, 0.f, 0.f, 0.f};
    float m_run[4], l_run[4];
    #pragma unroll
    for (int tt = 0; tt < 4; tt++) { m_run[tt] = -1e30f; l_run[tt] = 0.f; }

    for (int chunk = 0; chunk < NCHUNK; chunk++) {
        int keybase = chunk * 64;
        __syncthreads();
        {
            int key = tid >> 1;
            int ci0 = (tid & 1) << 5;
            int row = trow + keybase + key;
            row = row < (TP * HWP - 1) ? row : (TP * HWP - 1);
            const u32* src = (const u32*)(Vb + (kslab + row) * CID + ci0);
            int kk = key & 31;
            int col = ((key >> 5) << 5) + ((kk >> 2) & 3) * 8 + (kk >> 4) * 4 + (kk & 3);
            u16* dst = sVt + col;
            #pragma unroll
            for (int w = 0; w < 16; w++) {
                u32 v = src[w];
                dst[(ci0 + 2 * w) * 72]     = (u16)(v & 0xffffu);
                dst[(ci0 + 2 * w + 1) * 72] = (u16)(v >> 16);
            }
        }
        __syncthreads();

        short8 kfrag[4][2];
        #pragma unroll
        for (int g = 0; g < 4; g++) {
            int row = trow + keybase + g * 16 + l15;
            row = row < (TP * HWP - 1) ? row : (TP * HWP - 1);
            const uint4* kp = (const uint4*)(Kb + (kslab + row) * CID);
            kfrag[g][0] = *(const short8*)&kp[quad];
            kfrag[g][1] = *(const short8*)&kp[4 + quad];
        }
        short8 vfrag[4][2];
        #pragma unroll
        for (int cg = 0; cg < 4; cg++) {
            const u16* vp = sVt + (cg * 16 + l15) * 72;
            vfrag[cg][0] = *(const short8*)(vp + quad * 8);
            vfrag[cg][1] = *(const short8*)(vp + 32 + quad * 8);
        }

        bool lastchunk = (chunk == NCHUNK - 1);

        #pragma unroll
        for (int tt = 0; tt < 4; tt++) {
            floatx4 sc[4];
            #pragma unroll
            for (int g = 0; g < 4; g++) {
                sc[g] = (floatx4){0.f, 0.f, 0.f, 0.f};
                sc[g] = __builtin_amdgcn_mfma_f32_16x16x32_bf16(kfrag[g][0], qfrag[tt][0], sc[g], 0, 0, 0);
                sc[g] = __builtin_amdgcn_mfma_f32_16x16x32_bf16(kfrag[g][1], qfrag[tt][1], sc[g], 0, 0, 0);
            }
            if (lastchunk) {
                #pragma unroll
                for (int g = 0; g < 4; g++) {
                    int kb = keybase + g * 16 + quad * 4;
                    #pragma unroll
                    for (int r = 0; r < 4; r++)
                        if (kb + r >= NKEY) sc[g][r] = -1e30f;
                }
            }
            float cm = sc[0][0];
            #pragma unroll
            for (int g = 0; g < 4; g++)
                #pragma unroll
                for (int r = 0; r < 4; r++) cm = fmaxf(cm, sc[g][r]);
            cm = fmaxf(cm, __shfl_xor(cm, 16));
            cm = fmaxf(cm, __shfl_xor(cm, 32));
            float mnew = fmaxf(m_run[tt], cm);
            float alpha = __expf(m_run[tt] - mnew);
            m_run[tt] = mnew;

            float lsum = 0.f;
            u32 pw[8];
            #pragma unroll
            for (int g = 0; g < 4; g++) {
                float p0 = __expf(sc[g][0] - mnew);
                float p1 = __expf(sc[g][1] - mnew);
                float p2 = __expf(sc[g][2] - mnew);
                float p3 = __expf(sc[g][3] - mnew);
                lsum += (p0 + p1) + (p2 + p3);
                pw[g * 2 + 0] = pack2bf(p0, p1);
                pw[g * 2 + 1] = pack2bf(p2, p3);
            }
            lsum += __shfl_xor(lsum, 16);
            lsum += __shfl_xor(lsum, 32);
            l_run[tt] = l_run[tt] * alpha + lsum;

            float a0 = __shfl(alpha, quad * 4 + 0);
            float a1 = __shfl(alpha, quad * 4 + 1);
            float a2 = __shfl(alpha, quad * 4 + 2);
            float a3 = __shfl(alpha, quad * 4 + 3);

            union { u32 w[4]; short8 s; } pf0, pf1;
            pf0.w[0] = pw[0]; pf0.w[1] = pw[1]; pf0.w[2] = pw[2]; pf0.w[3] = pw[3];
            pf1.w[0] = pw[4]; pf1.w[1] = pw[5]; pf1.w[2] = pw[6]; pf1.w[3] = pw[7];

            #pragma unroll
            for (int cg = 0; cg < 4; cg++) {
                floatx4 ac = acc[tt][cg];
                ac[0] *= a0; ac[1] *= a1; ac[2] *= a2; ac[3] *= a3;
                ac = __builtin_amdgcn_mfma_f32_16x16x32_bf16(pf0.s, vfrag[cg][0], ac, 0, 0, 0);
                ac = __builtin_amdgcn_mfma_f32_16x16x32_bf16(pf1.s, vfrag[cg][1], ac, 0, 0, 0);
                acc[tt][cg] = ac;
            }
        }
    }

    #pragma unroll
    for (int tt = 0; tt < 4; tt++) {
        float linv = 1.0f / l_run[tt];
        float li[4];
        li[0] = __shfl(linv, quad * 4 + 0);
        li[1] = __shfl(linv, quad * 4 + 1);
        li[2] = __shfl(linv, quad * 4 + 2);
        li[3] = __shfl(linv, quad * 4 + 3);
        #pragma unroll
        for (int r = 0; r < 4; r++) {
            int p = (tilebase + tt) * 16 + quad * 4 + r;
            if (p < HWP) {
                #pragma unroll
                for (int cg = 0; cg < 4; cg++) {
                    int c = n * CID + cg * 16 + l15;
                    size_t addr = ((size_t)(b * CC + c) * TT + t) * HWP + p;
                    zout[addr] = acc[tt][cg][r] * li[r] + x[addr];
                }
            }
        }
    }
}

// ---------------------------------------------------------------------------
extern "C" void kernel_launch(void* const* d_in, const int* in_sizes, int n_in,
                              void* d_out, int out_size, void* d_ws, size_t ws_size,
                              hipStream_t stream) {
    const float* x  = (const float*)d_in[0];
    const float* Wq = (const float*)d_in[1];
    const float* bq = (const float*)d_in[2];
    const float* Wk = (const float*)d_in[3];
    const float* bk = (const float*)d_in[4];
    const float* Wv = (const float*)d_in[5];
    const float* bv = (const float*)d_in[6];
    float* z = (float*)d_out;

    const size_t qElems  = (size_t)BB * NH * TT * HWP * CID;  // 6,422,528
    const size_t kElems  = (size_t)BB * NH * TP * HWP * CID;  // 8,028,160
    const size_t xtElems = (size_t)MTOT * CC;                 // 6,422,528
    const size_t wElems  = (size_t)NTOT * CC;                 //   786,432

    u16* Qw = (u16*)d_ws;
    u16* Kw = Qw + qElems;
    u16* Vw = Kw + kElems;
    u16* Xt = Vw + kElems;
    u16* Wb = Xt + xtElems;

    const size_t need = (qElems + 2 * kElems + xtElems + wElems) * sizeof(u16);

    if (ws_size >= need) {
        convert_w<<<(NTOT * CC / 2 + 255) / 256, 256, 0, stream>>>(Wq, Wk, Wv, Wb);
        transpose_x<<<BB * TT * 8, 256, 0, stream>>>(x, Xt);
        pad_fill<<<(2 * 2 * NH * 8 * HWP * 32 + 255) / 256, 256, 0, stream>>>(bk, bv, Kw, Vw);
        proj_gemm<<<(MTOT / 64) * 6, 256, 0, stream>>>(Xt, Wb, bq, bk, bv, Qw, Kw, Vw);
    } else {
        proj_kernel<<<3584, 256, 0, stream>>>(x, Wq, bq, Wk, bk, Wv, bv, Qw, Kw, Vw);
    }
    attn_mfma<<<1024, 128, 0, stream>>>(x, Qw, Kw, Vw, z);
}